// Round 1
// baseline (455.739 us; speedup 1.0000x reference)
//
#include <hip/hip_runtime.h>

// ---------------- kernels ----------------

__global__ void k_zero(float* __restrict__ deg, int* __restrict__ cnt, int N) {
    int n = blockIdx.x * blockDim.x + threadIdx.x;
    if (n < N) { deg[n] = 0.0f; cnt[n] = 0; }
}

// xa[n][c] = mean_t x[n][c][t]; one wave per node, lane = channel
__global__ void k_mean(const float* __restrict__ x, float* __restrict__ xa, int N) {
    int tid = threadIdx.x;
    int n = blockIdx.x * 4 + (tid >> 6);
    if (n >= N) return;
    int c = tid & 63;
    const float4* xp = (const float4*)(x + (size_t)n * 1024 + (size_t)c * 16);
    float4 v0 = xp[0], v1 = xp[1], v2 = xp[2], v3 = xp[3];
    float s = ((v0.x + v0.y) + (v0.z + v0.w)) + ((v1.x + v1.y) + (v1.z + v1.w))
            + ((v2.x + v2.y) + (v2.z + v2.w)) + ((v3.x + v3.y) + (v3.z + v3.w));
    xa[(size_t)n * 64 + c] = s * 0.0625f;
}

// histogram: per-edge weighted degree (float) + edge count (int); cache ew compactly
__global__ void k_hist(const int* __restrict__ ei, const float* __restrict__ ea,
                       float* __restrict__ ewc, float* __restrict__ deg,
                       int* __restrict__ cnt, int E) {
    int e = blockIdx.x * blockDim.x + threadIdx.x;
    if (e >= E) return;
    int d = ei[E + e];
    float w = ea[(size_t)e * 16 + 15];
    ewc[e] = w;
    atomicAdd(deg + d, w);
    atomicAdd(cnt + d, 1);
}

__global__ void k_dinv(const float* __restrict__ deg, float* __restrict__ dinv, int N) {
    int n = blockIdx.x * blockDim.x + threadIdx.x;
    if (n < N) dinv[n] = 1.0f / sqrtf(deg[n] + 1.0f);
}

// block-wise inclusive scan of counts (1024/block)
__global__ void k_scan1(const int* __restrict__ cnt, int* __restrict__ incl,
                        int* __restrict__ parts, int N) {
    __shared__ int s[1024];
    int tid = threadIdx.x;
    int n = blockIdx.x * 1024 + tid;
    s[tid] = (n < N) ? cnt[n] : 0;
    __syncthreads();
    for (int off = 1; off < 1024; off <<= 1) {
        int t = (tid >= off) ? s[tid - off] : 0;
        __syncthreads();
        s[tid] += t;
        __syncthreads();
    }
    incl[n] = s[tid];
    if (tid == 1023) parts[blockIdx.x] = s[1023];
}

__global__ void k_scan2(int* __restrict__ parts, int nb) {
    if (threadIdx.x == 0 && blockIdx.x == 0) {
        int run = 0;
        for (int i = 0; i < nb; ++i) { int t = parts[i]; parts[i] = run; run += t; }
    }
}

__global__ void k_scan3(const int* __restrict__ incl, const int* __restrict__ cnt,
                        const int* __restrict__ parts, int* __restrict__ rs,
                        int* __restrict__ cur, int N) {
    int n = blockIdx.x * blockDim.x + threadIdx.x;
    if (n < N) {
        int v = incl[n] - cnt[n] + parts[n >> 10];
        rs[n] = v; cur[n] = v;
    }
}

// bucket edges by dst: srcs[] and precomputed norm[]
__global__ void k_scatter(const int* __restrict__ ei, const float* __restrict__ ewc,
                          const float* __restrict__ dinv, int* __restrict__ cur,
                          int* __restrict__ srcs, float* __restrict__ nrm, int E) {
    int e = blockIdx.x * blockDim.x + threadIdx.x;
    if (e >= E) return;
    int s = ei[e];
    int d = ei[E + e];
    float w = ewc[e];
    float nm = dinv[s] * w * dinv[d];
    int p = atomicAdd(cur + d, 1);
    srcs[p] = s;
    nrm[p] = nm;
}

// out[n] = in[n] @ W (+ bias); W (64x64) in LDS, input row in registers, 1 thread/node
__global__ void k_gemm64(const float* __restrict__ in, const float* __restrict__ W,
                         const float* __restrict__ bias, float* __restrict__ out, int N) {
    __shared__ float Wl[4096];
    int tid = threadIdx.x;
    {
        const float4* W4 = (const float4*)W;
        float4* Wl4 = (float4*)Wl;
        #pragma unroll
        for (int i = 0; i < 4; ++i) Wl4[i * 256 + tid] = W4[i * 256 + tid];
    }
    __syncthreads();
    int n = blockIdx.x * blockDim.x + tid;
    if (n >= N) return;

    float in_[64];
    const float4* ir = (const float4*)(in + (size_t)n * 64);
    #pragma unroll
    for (int i = 0; i < 16; ++i) {
        float4 v = ir[i];
        in_[4 * i + 0] = v.x; in_[4 * i + 1] = v.y;
        in_[4 * i + 2] = v.z; in_[4 * i + 3] = v.w;
    }
    float4 acc[16];
    if (bias) {
        const float4* b4 = (const float4*)bias;
        #pragma unroll
        for (int j = 0; j < 16; ++j) acc[j] = b4[j];
    } else {
        #pragma unroll
        for (int j = 0; j < 16; ++j) acc[j] = make_float4(0.f, 0.f, 0.f, 0.f);
    }
    const float4* Wl4 = (const float4*)Wl;
    #pragma unroll
    for (int c = 0; c < 64; ++c) {
        float ic = in_[c];
        #pragma unroll
        for (int j = 0; j < 16; ++j) {
            float4 w = Wl4[c * 16 + j];
            acc[j].x = fmaf(ic, w.x, acc[j].x);
            acc[j].y = fmaf(ic, w.y, acc[j].y);
            acc[j].z = fmaf(ic, w.z, acc[j].z);
            acc[j].w = fmaf(ic, w.w, acc[j].w);
        }
    }
    float4* orow = (float4*)(out + (size_t)n * 64);
    #pragma unroll
    for (int j = 0; j < 16; ++j) orow[j] = acc[j];
}

// GCN aggregation: one wave per node, lane = channel.
// out[n][c] = (RELU?) bias[c] + in[n][c]*dinv[n]^2 + sum_e in[src_e][c]*norm_e
template <int RELU>
__global__ void k_agg(const float* __restrict__ in, const float* __restrict__ bias,
                      const float* __restrict__ dinv, const int* __restrict__ rs,
                      const int* __restrict__ cnt, const int* __restrict__ srcs,
                      const float* __restrict__ nrm, float* __restrict__ out, int N) {
    int tid = threadIdx.x;
    int n = blockIdx.x * 4 + (tid >> 6);
    if (n >= N) return;
    int c = tid & 63;
    float dv = dinv[n];
    float acc = fmaf(in[(size_t)n * 64 + c] * dv, dv, bias[c]);
    int st = rs[n], m = cnt[n];
    for (int i = 0; i < m; ++i) {
        int s = srcs[st + i];
        float w = nrm[st + i];
        acc = fmaf(in[(size_t)s * 64 + c], w, acc);
    }
    if (RELU) acc = fmaxf(acc, 0.0f);
    out[(size_t)n * 64 + c] = acc;
}

// ---------------- launcher ----------------

extern "C" void kernel_launch(void* const* d_in, const int* in_sizes, int n_in,
                              void* d_out, int out_size, void* d_ws, size_t ws_size,
                              hipStream_t stream) {
    const float* x    = (const float*)d_in[0];
    const int*   ei   = (const int*)d_in[1];
    const float* ea   = (const float*)d_in[2];
    const float* W1   = (const float*)d_in[3];
    const float* b1   = (const float*)d_in[4];
    const float* W2   = (const float*)d_in[5];
    const float* b2   = (const float*)d_in[6];
    const float* Wout = (const float*)d_in[7];
    const float* bout = (const float*)d_in[8];
    float* out = (float*)d_out;

    const int N = in_sizes[0] / (64 * 16);   // 50000
    const int E = in_sizes[1] / 2;           // 800000
    const int nb = (N + 1023) / 1024;        // scan blocks
    const int NPAD = nb * 1024;

    float* ws = (float*)d_ws;
    size_t NC = (size_t)N * 64;
    float* A    = ws;             // xa, later h2
    float* B    = ws + NC;        // h1, later g (pre-Wout)
    float* C    = ws + 2 * NC;    // relu(h1 conv)
    float* deg  = ws + 3 * NC;
    float* dinv = deg + NPAD;
    int*   cnt  = (int*)(dinv + NPAD);
    int*   rs   = cnt + NPAD;
    int*   cur  = rs + NPAD;
    int*   incl = cur + NPAD;
    int*   parts= incl + NPAD;
    float* ewc  = (float*)(parts + 256);
    int*   srcs = (int*)(ewc + E);
    float* nrm  = (float*)(srcs + E);

    dim3 b256(256);
    hipLaunchKernelGGL(k_zero,   dim3((N + 255) / 256), b256, 0, stream, deg, cnt, N);
    hipLaunchKernelGGL(k_mean,   dim3((N + 3) / 4),     b256, 0, stream, x, A, N);
    hipLaunchKernelGGL(k_hist,   dim3((E + 255) / 256), b256, 0, stream, ei, ea, ewc, deg, cnt, E);
    hipLaunchKernelGGL(k_dinv,   dim3((N + 255) / 256), b256, 0, stream, deg, dinv, N);
    hipLaunchKernelGGL(k_scan1,  dim3(nb),  dim3(1024), 0, stream, cnt, incl, parts, N);
    hipLaunchKernelGGL(k_scan2,  dim3(1),   dim3(64),   0, stream, parts, nb);
    hipLaunchKernelGGL(k_scan3,  dim3((N + 255) / 256), b256, 0, stream, incl, cnt, parts, rs, cur, N);
    hipLaunchKernelGGL(k_scatter,dim3((E + 255) / 256), b256, 0, stream, ei, ewc, dinv, cur, srcs, nrm, E);

    // layer 1: h1 = xa @ W1 ; conv ; relu
    hipLaunchKernelGGL(k_gemm64, dim3((N + 255) / 256), b256, 0, stream, A, W1, (const float*)nullptr, B, N);
    hipLaunchKernelGGL((k_agg<1>), dim3((N + 3) / 4),   b256, 0, stream, B, b1, dinv, rs, cnt, srcs, nrm, C, N);
    // layer 2: h2 = C @ W2 ; conv
    hipLaunchKernelGGL(k_gemm64, dim3((N + 255) / 256), b256, 0, stream, C, W2, (const float*)nullptr, A, N);
    hipLaunchKernelGGL((k_agg<0>), dim3((N + 3) / 4),   b256, 0, stream, A, b2, dinv, rs, cnt, srcs, nrm, B, N);
    // output: out = B @ Wout + bout
    hipLaunchKernelGGL(k_gemm64, dim3((N + 255) / 256), b256, 0, stream, B, Wout, bout, out, N);
}

// Round 2
// 313.369 us; speedup vs baseline: 1.4543x; 1.4543x over previous
//
#include <hip/hip_runtime.h>

// ---------------- kernels ----------------

__global__ void k_zero(float* __restrict__ deg, int* __restrict__ cnt, int NPAD) {
    int n = blockIdx.x * blockDim.x + threadIdx.x;
    if (n < NPAD) { deg[n] = 0.0f; cnt[n] = 0; }
}

// Fused: xa = mean_t x ; h1 = xa @ W1. One wave per node (lane=channel), 16 nodes/block.
__global__ __launch_bounds__(256) void k_meanW1(const float* __restrict__ x,
                                                const float* __restrict__ W1,
                                                float* __restrict__ h1, int N) {
    __shared__ float Wl[4096];
    int tid = threadIdx.x;
    {
        const float4* W4 = (const float4*)W1;
        float4* Wl4 = (float4*)Wl;
        #pragma unroll
        for (int i = 0; i < 4; ++i) Wl4[i * 256 + tid] = W4[i * 256 + tid];
    }
    __syncthreads();
    int w = tid >> 6, c = tid & 63;
    for (int it = 0; it < 4; ++it) {
        int n = blockIdx.x * 16 + it * 4 + w;   // wave-uniform
        if (n >= N) continue;
        const float4* xp = (const float4*)(x + (size_t)n * 1024 + (size_t)c * 16);
        float4 v0 = xp[0], v1 = xp[1], v2 = xp[2], v3 = xp[3];
        float s = ((v0.x + v0.y) + (v0.z + v0.w)) + ((v1.x + v1.y) + (v1.z + v1.w))
                + ((v2.x + v2.y) + (v2.z + v2.w)) + ((v3.x + v3.y) + (v3.z + v3.w));
        float xa = s * 0.0625f;                 // lane c holds xa[n][c]
        float acc = 0.0f;                       // lane c computes h1[n][c]
        #pragma unroll
        for (int cc = 0; cc < 64; ++cc) {
            float rv = __shfl(xa, cc);
            acc = fmaf(rv, Wl[cc * 64 + c], acc);
        }
        h1[(size_t)n * 64 + c] = acc;
    }
}

// histogram: weighted degree (float) + edge count (int); compact ew cache
__global__ void k_hist(const int* __restrict__ ei, const float* __restrict__ ea,
                       float* __restrict__ ewc, float* __restrict__ deg,
                       int* __restrict__ cnt, int E) {
    int e = blockIdx.x * blockDim.x + threadIdx.x;
    if (e >= E) return;
    int d = ei[E + e];
    float w = ea[(size_t)e * 16 + 15];
    ewc[e] = w;
    atomicAdd(deg + d, w);
    atomicAdd(cnt + d, 1);
}

// block-wise inclusive scan of counts (1024/block) + fused dinv
__global__ void k_scan1(const int* __restrict__ cnt, int* __restrict__ incl,
                        int* __restrict__ parts, const float* __restrict__ deg,
                        float* __restrict__ dinv, int N) {
    __shared__ int s[1024];
    int tid = threadIdx.x;
    int n = blockIdx.x * 1024 + tid;
    s[tid] = (n < N) ? cnt[n] : 0;
    if (n < N) dinv[n] = 1.0f / sqrtf(deg[n] + 1.0f);
    __syncthreads();
    for (int off = 1; off < 1024; off <<= 1) {
        int t = (tid >= off) ? s[tid - off] : 0;
        __syncthreads();
        s[tid] += t;
        __syncthreads();
    }
    incl[n] = s[tid];
    if (tid == 1023) parts[blockIdx.x] = s[1023];
}

// wave-parallel exclusive scan of block partials (nb <= 64 here; nb=49)
__global__ void k_scan2(int* __restrict__ parts, int nb) {
    int l = threadIdx.x;
    if (nb <= 64) {
        int v = (l < nb) ? parts[l] : 0;
        #pragma unroll
        for (int off = 1; off < 64; off <<= 1) {
            int t = __shfl_up(v, off);
            if (l >= off) v += t;
        }
        int ex = __shfl_up(v, 1);
        if (l == 0) ex = 0;
        if (l < nb) parts[l] = ex;
    } else if (l == 0) {
        int run = 0;
        for (int i = 0; i < nb; ++i) { int t = parts[i]; parts[i] = run; run += t; }
    }
}

__global__ void k_scan3(const int* __restrict__ incl, const int* __restrict__ cnt,
                        const int* __restrict__ parts, int* __restrict__ rs,
                        int* __restrict__ cur, int N) {
    int n = blockIdx.x * blockDim.x + threadIdx.x;
    if (n < N) {
        int v = incl[n] - cnt[n] + parts[n >> 10];
        rs[n] = v; cur[n] = v;
    }
}

// bucket edges by dst: one int2 (src, norm-bits) per edge
__global__ void k_scatter(const int* __restrict__ ei, const float* __restrict__ ewc,
                          const float* __restrict__ dinv, int* __restrict__ cur,
                          int2* __restrict__ eb, int E) {
    int e = blockIdx.x * blockDim.x + threadIdx.x;
    if (e >= E) return;
    int s = ei[e];
    int d = ei[E + e];
    float nm = dinv[s] * ewc[e] * dinv[d];
    int p = atomicAdd(cur + d, 1);
    eb[p] = make_int2(s, __float_as_int(nm));
}

// Fused GCN aggregation + row GEMM. One wave per node, lane = channel.
// r = [relu]( bias[c] + in[n][c]*dinv^2 + sum_e in[src][c]*norm )
// out[n][c] = sum_cc r[cc] * Wm[cc][c]  (+ bout[c])
template <int RELU, int HAS_BOUT>
__global__ __launch_bounds__(256) void k_aggW(const float* __restrict__ in,
                                              const float* __restrict__ bias,
                                              const float* __restrict__ Wm,
                                              const float* __restrict__ bout,
                                              const float* __restrict__ dinv,
                                              const int* __restrict__ rs,
                                              const int* __restrict__ cnt,
                                              const int2* __restrict__ eb,
                                              float* __restrict__ out, int N) {
    __shared__ float Wl[4096];
    int tid = threadIdx.x;
    {
        const float4* W4 = (const float4*)Wm;
        float4* Wl4 = (float4*)Wl;
        #pragma unroll
        for (int i = 0; i < 4; ++i) Wl4[i * 256 + tid] = W4[i * 256 + tid];
    }
    __syncthreads();
    int w = tid >> 6, c = tid & 63;
    for (int it = 0; it < 4; ++it) {
        int n = blockIdx.x * 16 + it * 4 + w;   // wave-uniform
        if (n >= N) continue;
        float dv = dinv[n];
        float a0 = fmaf(in[(size_t)n * 64 + c] * dv, dv, bias[c]);
        float a1 = 0.f, a2 = 0.f, a3 = 0.f;
        int st = rs[n], m = cnt[n];
        int i = 0;
        for (; i + 4 <= m; i += 4) {
            int2 e0 = eb[st + i], e1 = eb[st + i + 1], e2 = eb[st + i + 2], e3 = eb[st + i + 3];
            a0 = fmaf(in[(size_t)e0.x * 64 + c], __int_as_float(e0.y), a0);
            a1 = fmaf(in[(size_t)e1.x * 64 + c], __int_as_float(e1.y), a1);
            a2 = fmaf(in[(size_t)e2.x * 64 + c], __int_as_float(e2.y), a2);
            a3 = fmaf(in[(size_t)e3.x * 64 + c], __int_as_float(e3.y), a3);
        }
        for (; i < m; ++i) {
            int2 e = eb[st + i];
            a0 = fmaf(in[(size_t)e.x * 64 + c], __int_as_float(e.y), a0);
        }
        float r = (a0 + a1) + (a2 + a3);
        if (RELU) r = fmaxf(r, 0.0f);
        float acc = HAS_BOUT ? bout[c] : 0.0f;
        #pragma unroll
        for (int cc = 0; cc < 64; ++cc) {
            float rv = __shfl(r, cc);
            acc = fmaf(rv, Wl[cc * 64 + c], acc);
        }
        out[(size_t)n * 64 + c] = acc;
    }
}

// ---------------- launcher ----------------

extern "C" void kernel_launch(void* const* d_in, const int* in_sizes, int n_in,
                              void* d_out, int out_size, void* d_ws, size_t ws_size,
                              hipStream_t stream) {
    const float* x    = (const float*)d_in[0];
    const int*   ei   = (const int*)d_in[1];
    const float* ea   = (const float*)d_in[2];
    const float* W1   = (const float*)d_in[3];
    const float* b1   = (const float*)d_in[4];
    const float* W2   = (const float*)d_in[5];
    const float* b2   = (const float*)d_in[6];
    const float* Wout = (const float*)d_in[7];
    const float* bout = (const float*)d_in[8];
    float* out = (float*)d_out;

    const int N = in_sizes[0] / (64 * 16);   // 50000
    const int E = in_sizes[1] / 2;           // 800000
    const int nb = (N + 1023) / 1024;        // 49
    const int NPAD = nb * 1024;

    float* ws = (float*)d_ws;
    size_t NC = (size_t)N * 64;
    float* H1   = ws;                 // h1 = xa@W1 ; gather source of layer 1
    float* H2   = ws + NC;            // relu(conv1)@W2 ; gather source of layer 2
    float* deg  = ws + 2 * NC;
    int*   cnt  = (int*)(deg + NPAD);
    float* dinv = (float*)(cnt + NPAD);
    int*   rs   = (int*)(dinv + NPAD);
    int*   cur  = rs + NPAD;
    int*   incl = cur + NPAD;
    int*   parts= incl + NPAD;
    float* ewc  = (float*)(parts + 256);
    int2*  eb   = (int2*)(ewc + E);   // even float offset -> 8B aligned

    dim3 b256(256);
    int nodeBlocks = (N + 15) / 16;
    hipLaunchKernelGGL(k_zero,   dim3((2 * NPAD + 255) / 256), b256, 0, stream, deg, cnt, 2 * NPAD);
    hipLaunchKernelGGL(k_meanW1, dim3(nodeBlocks), b256, 0, stream, x, W1, H1, N);
    hipLaunchKernelGGL(k_hist,   dim3((E + 255) / 256), b256, 0, stream, ei, ea, ewc, deg, cnt, E);
    hipLaunchKernelGGL(k_scan1,  dim3(nb), dim3(1024), 0, stream, cnt, incl, parts, deg, dinv, N);
    hipLaunchKernelGGL(k_scan2,  dim3(1),  dim3(64),   0, stream, parts, nb);
    hipLaunchKernelGGL(k_scan3,  dim3((N + 255) / 256), b256, 0, stream, incl, cnt, parts, rs, cur, N);
    hipLaunchKernelGGL(k_scatter,dim3((E + 255) / 256), b256, 0, stream, ei, ewc, dinv, cur, eb, E);

    // layer 1 conv (+b1, relu) fused with @W2  -> H2
    hipLaunchKernelGGL((k_aggW<1, 0>), dim3(nodeBlocks), b256, 0, stream,
                       H1, b1, W2, (const float*)nullptr, dinv, rs, cnt, eb, H2, N);
    // layer 2 conv (+b2) fused with @Wout + bout -> out
    hipLaunchKernelGGL((k_aggW<0, 1>), dim3(nodeBlocks), b256, 0, stream,
                       H2, b2, Wout, bout, dinv, rs, cnt, eb, out, N);
}

// Round 3
// 282.140 us; speedup vs baseline: 1.6153x; 1.1107x over previous
//
#include <hip/hip_runtime.h>

// ---------------- kernels ----------------

__global__ void k_zero(float* __restrict__ deg, int* __restrict__ cnt, int NPAD) {
    int n = blockIdx.x * blockDim.x + threadIdx.x;
    if (n < NPAD) { deg[n] = 0.0f; cnt[n] = 0; }
}

// Fat kernel: blocks [0, meanBlocks) -> mean+W1 (one wave per node, 16 nodes/block)
//             blocks [meanBlocks, ...) -> edge histogram (256 edges/block)
// Both memory-bound on different data; merging overlaps them.
__global__ __launch_bounds__(256) void k_meanhist(const float* __restrict__ x,
                                                  const float* __restrict__ W1,
                                                  float* __restrict__ h1, int N,
                                                  const int* __restrict__ ei,
                                                  const float* __restrict__ ea,
                                                  float* __restrict__ ewc,
                                                  float* __restrict__ deg,
                                                  int* __restrict__ cnt, int E,
                                                  int meanBlocks) {
    int tid = threadIdx.x;
    if ((int)blockIdx.x >= meanBlocks) {
        int e = ((int)blockIdx.x - meanBlocks) * 256 + tid;
        if (e < E) {
            int d = ei[E + e];
            float w = ea[(size_t)e * 16 + 15];
            ewc[e] = w;
            atomicAdd(deg + d, w);
            atomicAdd(cnt + d, 1);
        }
        return;
    }
    __shared__ float Wl[4096];
    {
        const float4* W4 = (const float4*)W1;
        float4* Wl4 = (float4*)Wl;
        #pragma unroll
        for (int i = 0; i < 4; ++i) Wl4[i * 256 + tid] = W4[i * 256 + tid];
    }
    __syncthreads();
    int w = tid >> 6, c = tid & 63;
    for (int it = 0; it < 4; ++it) {
        int n = blockIdx.x * 16 + it * 4 + w;   // wave-uniform
        if (n >= N) continue;
        const float4* xp = (const float4*)(x + (size_t)n * 1024 + (size_t)c * 16);
        float4 v0 = xp[0], v1 = xp[1], v2 = xp[2], v3 = xp[3];
        float s = ((v0.x + v0.y) + (v0.z + v0.w)) + ((v1.x + v1.y) + (v1.z + v1.w))
                + ((v2.x + v2.y) + (v2.z + v2.w)) + ((v3.x + v3.y) + (v3.z + v3.w));
        float xa = s * 0.0625f;                 // lane c holds xa[n][c]
        float acc = 0.0f;
        #pragma unroll
        for (int cc = 0; cc < 64; ++cc) {
            float rv = __shfl(xa, cc);
            acc = fmaf(rv, Wl[cc * 64 + c], acc);
        }
        h1[(size_t)n * 64 + c] = acc;
    }
}

// block-wise inclusive scan of counts (1024/block) + fused dinv
__global__ void k_scan1(const int* __restrict__ cnt, int* __restrict__ incl,
                        int* __restrict__ parts, const float* __restrict__ deg,
                        float* __restrict__ dinv, int N) {
    __shared__ int s[1024];
    int tid = threadIdx.x;
    int n = blockIdx.x * 1024 + tid;
    s[tid] = (n < N) ? cnt[n] : 0;
    if (n < N) dinv[n] = 1.0f / sqrtf(deg[n] + 1.0f);
    __syncthreads();
    for (int off = 1; off < 1024; off <<= 1) {
        int t = (tid >= off) ? s[tid - off] : 0;
        __syncthreads();
        s[tid] += t;
        __syncthreads();
    }
    incl[n] = s[tid];
    if (tid == 1023) parts[blockIdx.x] = s[1023];
}

// fused: each block computes its own exclusive block-offset from parts (nb<=64)
// then finalizes rs/cur. 1024 threads/block, nb blocks.
__global__ void k_scan23(const int* __restrict__ incl, const int* __restrict__ cnt,
                         const int* __restrict__ parts, int* __restrict__ rs,
                         int* __restrict__ cur, int N, int nb) {
    __shared__ int soff;
    int tid = threadIdx.x;
    if (tid < 64) {
        int v = (tid < nb && tid < (int)blockIdx.x) ? parts[tid] : 0;
        #pragma unroll
        for (int off = 32; off >= 1; off >>= 1) v += __shfl_down(v, off);
        if (tid == 0) soff = v;
    }
    __syncthreads();
    int n = blockIdx.x * 1024 + tid;
    if (n < N) {
        int v = incl[n] - cnt[n] + soff;
        rs[n] = v; cur[n] = v;
    }
}

// bucket edges by dst: one int2 (src, norm-bits) per edge
__global__ void k_scatter(const int* __restrict__ ei, const float* __restrict__ ewc,
                          const float* __restrict__ dinv, int* __restrict__ cur,
                          int2* __restrict__ eb, int E) {
    int e = blockIdx.x * blockDim.x + threadIdx.x;
    if (e >= E) return;
    int s = ei[e];
    int d = ei[E + e];
    float nm = dinv[s] * ewc[e] * dinv[d];
    int p = atomicAdd(cur + d, 1);
    eb[p] = make_int2(s, __float_as_int(nm));
}

// Fused GCN aggregation + row GEMM. One wave per node, lane = channel.
// 8 outstanding gathers to cover L2/L3 latency.
template <int RELU, int HAS_BOUT>
__global__ __launch_bounds__(256) void k_aggW(const float* __restrict__ in,
                                              const float* __restrict__ bias,
                                              const float* __restrict__ Wm,
                                              const float* __restrict__ bout,
                                              const float* __restrict__ dinv,
                                              const int* __restrict__ rs,
                                              const int* __restrict__ cnt,
                                              const int2* __restrict__ eb,
                                              float* __restrict__ out, int N) {
    __shared__ float Wl[4096];
    int tid = threadIdx.x;
    {
        const float4* W4 = (const float4*)Wm;
        float4* Wl4 = (float4*)Wl;
        #pragma unroll
        for (int i = 0; i < 4; ++i) Wl4[i * 256 + tid] = W4[i * 256 + tid];
    }
    __syncthreads();
    int w = tid >> 6, c = tid & 63;
    for (int it = 0; it < 4; ++it) {
        int n = blockIdx.x * 16 + it * 4 + w;   // wave-uniform
        if (n >= N) continue;
        float dv = dinv[n];
        float a0 = fmaf(in[(size_t)n * 64 + c] * dv, dv, bias[c]);
        float a1 = 0.f, a2 = 0.f, a3 = 0.f;
        int st = rs[n], m = cnt[n];
        int i = 0;
        for (; i + 8 <= m; i += 8) {
            int2 e0 = eb[st + i + 0], e1 = eb[st + i + 1];
            int2 e2 = eb[st + i + 2], e3 = eb[st + i + 3];
            int2 e4 = eb[st + i + 4], e5 = eb[st + i + 5];
            int2 e6 = eb[st + i + 6], e7 = eb[st + i + 7];
            float v0 = in[(size_t)e0.x * 64 + c], v1 = in[(size_t)e1.x * 64 + c];
            float v2 = in[(size_t)e2.x * 64 + c], v3 = in[(size_t)e3.x * 64 + c];
            float v4 = in[(size_t)e4.x * 64 + c], v5 = in[(size_t)e5.x * 64 + c];
            float v6 = in[(size_t)e6.x * 64 + c], v7 = in[(size_t)e7.x * 64 + c];
            a0 = fmaf(v0, __int_as_float(e0.y), a0);
            a1 = fmaf(v1, __int_as_float(e1.y), a1);
            a2 = fmaf(v2, __int_as_float(e2.y), a2);
            a3 = fmaf(v3, __int_as_float(e3.y), a3);
            a0 = fmaf(v4, __int_as_float(e4.y), a0);
            a1 = fmaf(v5, __int_as_float(e5.y), a1);
            a2 = fmaf(v6, __int_as_float(e6.y), a2);
            a3 = fmaf(v7, __int_as_float(e7.y), a3);
        }
        for (; i + 4 <= m; i += 4) {
            int2 e0 = eb[st + i], e1 = eb[st + i + 1], e2 = eb[st + i + 2], e3 = eb[st + i + 3];
            float v0 = in[(size_t)e0.x * 64 + c], v1 = in[(size_t)e1.x * 64 + c];
            float v2 = in[(size_t)e2.x * 64 + c], v3 = in[(size_t)e3.x * 64 + c];
            a0 = fmaf(v0, __int_as_float(e0.y), a0);
            a1 = fmaf(v1, __int_as_float(e1.y), a1);
            a2 = fmaf(v2, __int_as_float(e2.y), a2);
            a3 = fmaf(v3, __int_as_float(e3.y), a3);
        }
        for (; i < m; ++i) {
            int2 e = eb[st + i];
            a0 = fmaf(in[(size_t)e.x * 64 + c], __int_as_float(e.y), a0);
        }
        float r = (a0 + a1) + (a2 + a3);
        if (RELU) r = fmaxf(r, 0.0f);
        float acc = HAS_BOUT ? bout[c] : 0.0f;
        #pragma unroll
        for (int cc = 0; cc < 64; ++cc) {
            float rv = __shfl(r, cc);
            acc = fmaf(rv, Wl[cc * 64 + c], acc);
        }
        out[(size_t)n * 64 + c] = acc;
    }
}

// ---------------- launcher ----------------

extern "C" void kernel_launch(void* const* d_in, const int* in_sizes, int n_in,
                              void* d_out, int out_size, void* d_ws, size_t ws_size,
                              hipStream_t stream) {
    const float* x    = (const float*)d_in[0];
    const int*   ei   = (const int*)d_in[1];
    const float* ea   = (const float*)d_in[2];
    const float* W1   = (const float*)d_in[3];
    const float* b1   = (const float*)d_in[4];
    const float* W2   = (const float*)d_in[5];
    const float* b2   = (const float*)d_in[6];
    const float* Wout = (const float*)d_in[7];
    const float* bout = (const float*)d_in[8];
    float* out = (float*)d_out;

    const int N = in_sizes[0] / (64 * 16);   // 50000
    const int E = in_sizes[1] / 2;           // 800000
    const int nb = (N + 1023) / 1024;        // 49
    const int NPAD = nb * 1024;

    float* ws = (float*)d_ws;
    size_t NC = (size_t)N * 64;
    float* H1   = ws;                 // h1 = xa@W1 ; gather source of layer 1
    float* H2   = ws + NC;            // relu(conv1)@W2 ; gather source of layer 2
    float* deg  = ws + 2 * NC;
    int*   cnt  = (int*)(deg + NPAD);
    float* dinv = (float*)(cnt + NPAD);
    int*   rs   = (int*)(dinv + NPAD);
    int*   cur  = rs + NPAD;
    int*   incl = cur + NPAD;
    int*   parts= incl + NPAD;
    float* ewc  = (float*)(parts + 256);
    int2*  eb   = (int2*)(ewc + E);   // even float offset -> 8B aligned

    dim3 b256(256);
    int meanBlocks = (N + 15) / 16;          // 3125
    int histBlocks = (E + 255) / 256;        // 3125
    hipLaunchKernelGGL(k_zero,     dim3((2 * NPAD + 255) / 256), b256, 0, stream, deg, cnt, 2 * NPAD);
    hipLaunchKernelGGL(k_meanhist, dim3(meanBlocks + histBlocks), b256, 0, stream,
                       x, W1, H1, N, ei, ea, ewc, deg, cnt, E, meanBlocks);
    hipLaunchKernelGGL(k_scan1,    dim3(nb), dim3(1024), 0, stream, cnt, incl, parts, deg, dinv, N);
    hipLaunchKernelGGL(k_scan23,   dim3(nb), dim3(1024), 0, stream, incl, cnt, parts, rs, cur, N, nb);
    hipLaunchKernelGGL(k_scatter,  dim3((E + 255) / 256), b256, 0, stream, ei, ewc, dinv, cur, eb, E);

    // layer 1 conv (+b1, relu) fused with @W2  -> H2
    hipLaunchKernelGGL((k_aggW<1, 0>), dim3(meanBlocks), b256, 0, stream,
                       H1, b1, W2, (const float*)nullptr, dinv, rs, cnt, eb, H2, N);
    // layer 2 conv (+b2) fused with @Wout + bout -> out
    hipLaunchKernelGGL((k_aggW<0, 1>), dim3(meanBlocks), b256, 0, stream,
                       H2, b2, Wout, bout, dinv, rs, cnt, eb, out, N);
}